// Round 5
// baseline (741.756 us; speedup 1.0000x reference)
//
#include <hip/hip_runtime.h>
#include <cstdint>
#include <cstddef>

typedef unsigned short u16;
typedef unsigned int   u32;
typedef short s16x8 __attribute__((ext_vector_type(8)));   // 8 bf16 bit-patterns (4 VGPRs)
typedef float f32x4 __attribute__((ext_vector_type(4)));

#define B_   4
#define H_   16
#define N_   2048
#define M_   2048
#define D_   1024
#define ROWS 8192   // B_*N_ == B_*M_

// ---------- scalar helpers ----------
__device__ __forceinline__ u16 f2bf(float x){
  u32 u = __builtin_bit_cast(u32, x);
  u = (u + 0x7fffu + ((u >> 16) & 1u)) >> 16;   // RNE truncate to bf16
  return (u16)u;
}
__device__ __forceinline__ float bf2f(u16 h){
  u32 u = ((u32)h) << 16;
  return __builtin_bit_cast(float, u);
}
__device__ __forceinline__ void split2(float v, u16 &h, u16 &l){
  h = f2bf(v);
  l = f2bf(v - bf2f(h));
}
__device__ __forceinline__ void gload16(const void* g, void* l){
  __builtin_amdgcn_global_load_lds((const __attribute__((address_space(1))) u32*)g,
                                   (__attribute__((address_space(3))) u32*)l, 16, 0, 0);
}
__device__ __forceinline__ f32x4 mfma16(s16x8 a, s16x8 b, f32x4 c){
  return __builtin_amdgcn_mfma_f32_16x16x32_bf16(a, b, c, 0, 0, 0);
}

// ---------- kernel 1: split X and M into bf16 hi/lo ----------
__global__ void split_xm(const float* __restrict__ X, const float* __restrict__ Mi,
                         u16* __restrict__ Xh, u16* __restrict__ Xl,
                         u16* __restrict__ Mh, u16* __restrict__ Ml){
  const int n4 = ROWS * D_ / 4;
  for (int i = blockIdx.x * blockDim.x + threadIdx.x; i < n4; i += gridDim.x * blockDim.x){
    float4 x = ((const float4*)X)[i];
    float4 m = ((const float4*)Mi)[i];
    ushort4 xh, xl, mh, ml;
    split2(x.x, xh.x, xl.x); split2(x.y, xh.y, xl.y);
    split2(x.z, xh.z, xl.z); split2(x.w, xh.w, xl.w);
    split2(m.x, mh.x, ml.x); split2(m.y, mh.y, ml.y);
    split2(m.z, mh.z, ml.z); split2(m.w, mh.w, ml.w);
    ((ushort4*)Xh)[i] = xh; ((ushort4*)Xl)[i] = xl;
    ((ushort4*)Mh)[i] = mh; ((ushort4*)Ml)[i] = ml;
  }
}

// ---------- kernel 2: weight transposes + hi/lo splits ----------
__global__ void transform_w(const float* __restrict__ Pq, const float* __restrict__ Pk,
                            const float* __restrict__ Pv, const float* __restrict__ Po,
                            u16* __restrict__ PqTh, u16* __restrict__ PqTl,
                            u16* __restrict__ PkvTh, u16* __restrict__ PkvTl,
                            u16* __restrict__ WoTh, u16* __restrict__ WoTl){
  const int TOT = 1048576 + 131072 + 1048576;
  for (int gid = blockIdx.x * blockDim.x + threadIdx.x; gid < TOT; gid += gridDim.x * blockDim.x){
    float v; u16 *oh, *ol; int oidx;
    if (gid < 1048576){
      int c = gid >> 10, d = gid & 1023;
      v = Pq[(size_t)(c >> 6) * 65536 + d * 64 + (c & 63)];
      oh = PqTh; ol = PqTl; oidx = gid;
    } else if (gid < 1048576 + 131072){
      int t = gid - 1048576; int c = t >> 10, d = t & 1023;
      v = (c < 64) ? Pk[d * 64 + c] : Pv[d * 64 + (c - 64)];
      oh = PkvTh; ol = PkvTl; oidx = t;
    } else {
      int t = gid - (1048576 + 131072); int dd = t >> 10, hv = t & 1023;
      v = Po[(size_t)(hv >> 6) * 65536 + dd * 64 + (hv & 63)];
      oh = WoTh; ol = WoTl; oidx = t;
    }
    u16 h, l; split2(v, h, l);
    oh[oidx] = h; ol[oidx] = l;
  }
}

// ---------- shared GEMM (unchanged this round) ----------
template<int MODE>
__global__ __launch_bounds__(256, 2)
void gemm3(const u16* __restrict__ Ah, const u16* __restrict__ Al,
           const u16* __restrict__ Bh, const u16* __restrict__ Bl,
           void* __restrict__ o0, void* __restrict__ o1, void* __restrict__ o2){
  __shared__ __align__(16) u16 lds[2][4][128 * 32];
  const int tid = threadIdx.x;
  const int lane = tid & 63;
  const int w = tid >> 6;
  const int wr = w >> 1, wc = w & 1;
  const int br0 = blockIdx.y * 128;
  const int bc0 = blockIdx.x * 128;

  const u16* srcs[4] = {Ah, Al, Bh, Bl};

  auto stage = [&](int buf, int s){
    const int k0 = s * 32;
#pragma unroll
    for (int t = 0; t < 4; t++){
      const u16* src = srcs[t];
      const int rbase = (t >= 2) ? bc0 : br0;
#pragma unroll
      for (int it = 0; it < 2; it++){
        const int c1k = w * 2 + it;
        const int ci = c1k * 64 + lane;
        const int row = ci >> 2;
        const int gs = (ci & 3) ^ ((row >> 1) & 3);
        gload16(src + (size_t)(rbase + row) * 1024 + k0 + gs * 8,
                &lds[buf][t][c1k * 512]);
      }
    }
  };

  f32x4 acc[4][4];
#pragma unroll
  for (int i = 0; i < 4; i++)
#pragma unroll
    for (int j = 0; j < 4; j++) acc[i][j] = f32x4{0.f, 0.f, 0.f, 0.f};

  stage(0, 0);
  for (int s = 0; s < 32; s++){
    __syncthreads();
    if (s + 1 < 32) stage((s + 1) & 1, s + 1);
    const int buf = s & 1;
    const int g = lane >> 4;
    s16x8 fah[4], fal[4], fbh[4], fbl[4];
#pragma unroll
    for (int i = 0; i < 4; i++){
      const int ra = wr * 64 + i * 16 + (lane & 15);
      const int oa = ra * 64 + ((g ^ ((ra >> 1) & 3)) * 16);
      fah[i] = *(const s16x8*)((const char*)&lds[buf][0][0] + oa);
      fal[i] = *(const s16x8*)((const char*)&lds[buf][1][0] + oa);
      const int rb = wc * 64 + i * 16 + (lane & 15);
      const int ob = rb * 64 + ((g ^ ((rb >> 1) & 3)) * 16);
      fbh[i] = *(const s16x8*)((const char*)&lds[buf][2][0] + ob);
      fbl[i] = *(const s16x8*)((const char*)&lds[buf][3][0] + ob);
    }
#pragma unroll
    for (int i = 0; i < 4; i++)
#pragma unroll
      for (int j = 0; j < 4; j++){
        acc[i][j] = mfma16(fah[i], fbh[j], acc[i][j]);
        acc[i][j] = mfma16(fah[i], fbl[j], acc[i][j]);
        acc[i][j] = mfma16(fal[i], fbh[j], acc[i][j]);
      }
  }

#pragma unroll
  for (int i = 0; i < 4; i++){
#pragma unroll
    for (int j = 0; j < 4; j++){
#pragma unroll
      for (int r = 0; r < 4; r++){
        const int row = br0 + wr * 64 + i * 16 + (lane >> 4) * 4 + r;
        const int col = bc0 + wc * 64 + j * 16 + (lane & 15);
        const float v = acc[i][j][r];
        if (MODE == 0){
          const int b = row >> 11, n = row & 2047;
          const int h = col >> 6,  k = col & 63;
          const size_t idx = ((size_t)(b * H_ + h) * N_ + n) * 64 + k;
          u16 hh, ll; split2(v, hh, ll);
          ((u16*)o0)[idx] = hh; ((u16*)o1)[idx] = ll;
        } else if (MODE == 1){
          if (col < 64){
            const size_t idx = (size_t)row * 64 + col;
            u16 hh, ll; split2(v, hh, ll);
            ((u16*)o0)[idx] = hh; ((u16*)o1)[idx] = ll;
          } else {
            const int b = row >> 11, m = row & 2047;
            const size_t idx = (size_t)b * (64 * 2048) + (size_t)(col - 64) * 2048 + m;
            ((u16*)o2)[idx] = f2bf(v);
          }
        } else {
          ((float*)o0)[(size_t)row * 1024 + col] = v;
        }
      }
    }
  }
}

// ---------- attention step: one 32-m tile, prefetching next tile's K ----------
__device__ __forceinline__ void loadK(s16x8 (&KH)[2][2], s16x8 (&KL)[2][2],
                                      const u16* kph, const u16* kpl, int eoff){
#pragma unroll
  for (int mt = 0; mt < 2; mt++)
#pragma unroll
    for (int kc = 0; kc < 2; kc++){
      const size_t o = (size_t)eoff + mt * 1024 + kc * 32;
      KH[mt][kc] = *(const s16x8*)(kph + o);
      KL[mt][kc] = *(const s16x8*)(kpl + o);
    }
}

__device__ __forceinline__ void attn_step(
    const s16x8 (&KHC)[2][2], const s16x8 (&KLC)[2][2],
    s16x8 (&KHN)[2][2], s16x8 (&KLN)[2][2], int m0,
    const s16x8 (&fqh)[2][2], const s16x8 (&fql)[2][2],
    f32x4 (&acc)[2][4], float (&mrun)[2], float (&lrun)[2],
    const float* const (&mrow)[2], const u16* vp,
    const u16* kph, const u16* kpl, u16* pl, int c, int g){
  // current-tile mask + V loads issued first (consumed after the QK MFMA block)
  float4 mk[2][2];
#pragma unroll
  for (int qt = 0; qt < 2; qt++)
#pragma unroll
    for (int mt = 0; mt < 2; mt++)
      mk[qt][mt] = *(const float4*)(mrow[qt] + m0 + mt * 16);
  s16x8 fv[4];
#pragma unroll
  for (int vt = 0; vt < 4; vt++)
    fv[vt] = *(const s16x8*)(vp + (size_t)vt * 16 * M_ + m0);
  // prefetch NEXT tile's K (wrapped at the end; the extra loads are dead but valid)
  loadK(KHN, KLN, kph, kpl, ((m0 + 32) & (M_ - 1)) * 64);
  // S^T = mfma(K, Q), split-3
  f32x4 S[2][2];
#pragma unroll
  for (int qt = 0; qt < 2; qt++)
#pragma unroll
    for (int mt = 0; mt < 2; mt++){
      f32x4 a = f32x4{0.f, 0.f, 0.f, 0.f};
      a = mfma16(KHC[mt][0], fqh[qt][0], a);
      a = mfma16(KHC[mt][1], fqh[qt][1], a);
      a = mfma16(KLC[mt][0], fqh[qt][0], a);
      a = mfma16(KLC[mt][1], fqh[qt][1], a);
      a = mfma16(KHC[mt][0], fql[qt][0], a);
      a = mfma16(KHC[mt][1], fql[qt][1], a);
      S[qt][mt] = a;
    }
#pragma unroll
  for (int qt = 0; qt < 2; qt++){
    S[qt][0][0] += mk[qt][0].x; S[qt][0][1] += mk[qt][0].y;
    S[qt][0][2] += mk[qt][0].z; S[qt][0][3] += mk[qt][0].w;
    S[qt][1][0] += mk[qt][1].x; S[qt][1][1] += mk[qt][1].y;
    S[qt][1][2] += mk[qt][1].z; S[qt][1][3] += mk[qt][1].w;
  }
  // branchless online softmax (lane-local 8-val max, 2 shfl, unconditional rescale)
#pragma unroll
  for (int qt = 0; qt < 2; qt++){
    float rmax = fmaxf(fmaxf(fmaxf(S[qt][0][0], S[qt][0][1]), fmaxf(S[qt][0][2], S[qt][0][3])),
                       fmaxf(fmaxf(S[qt][1][0], S[qt][1][1]), fmaxf(S[qt][1][2], S[qt][1][3])));
    rmax = fmaxf(rmax, __shfl_xor(rmax, 16, 64));
    rmax = fmaxf(rmax, __shfl_xor(rmax, 32, 64));
    const float mnew = fmaxf(mrun[qt], rmax);
    const float sc = __expf(mrun[qt] - mnew);
    mrun[qt] = mnew;
#pragma unroll
    for (int vt = 0; vt < 4; vt++){
      acc[qt][vt][0] *= sc; acc[qt][vt][1] *= sc;
      acc[qt][vt][2] *= sc; acc[qt][vt][3] *= sc;
    }
    float psum = 0.f;
#pragma unroll
    for (int mt = 0; mt < 2; mt++){
      float p0 = __expf(S[qt][mt][0] - mnew);
      float p1 = __expf(S[qt][mt][1] - mnew);
      float p2 = __expf(S[qt][mt][2] - mnew);
      float p3 = __expf(S[qt][mt][3] - mnew);
      psum += (p0 + p1) + (p2 + p3);
      ushort4 pk;
      pk.x = f2bf(p0); pk.y = f2bf(p1); pk.z = f2bf(p2); pk.w = f2bf(p3);
      *(ushort4*)((char*)pl + (qt * 16 + c) * 80 + mt * 32 + g * 8) = pk;
    }
    lrun[qt] = lrun[qt] * sc + psum;
  }
  // P^T B-frags (same-wave DS ordering; compiler inserts lgkmcnt wait)
  s16x8 pb0 = *(const s16x8*)((const char*)pl + c * 80 + g * 16);
  s16x8 pb1 = *(const s16x8*)((const char*)pl + (16 + c) * 80 + g * 16);
  // swapped PV: O^T += mfma(V^T, P^T)
#pragma unroll
  for (int vt = 0; vt < 4; vt++){
    acc[0][vt] = mfma16(fv[vt], pb0, acc[0][vt]);
    acc[1][vt] = mfma16(fv[vt], pb1, acc[1][vt]);
  }
}

// ---------- kernel 5: flash attention (swapped-operand, K-prefetch pipeline) ----------
__global__ __launch_bounds__(256)
void attn(const u16* __restrict__ Qh, const u16* __restrict__ Ql,
          const u16* __restrict__ Kh, const u16* __restrict__ Kl,
          const u16* __restrict__ VT, const float* __restrict__ mask,
          u16* __restrict__ Oh, u16* __restrict__ Ol){
  __shared__ __align__(16) u16 plds[4][32 * 40];   // per-wave P scratch [q][m], stride 40 u16
  const int lane = threadIdx.x & 63;
  const int w = threadIdx.x >> 6;
  const int g = lane >> 4;                 // 4 lane-groups: m sub-rows
  const int c = lane & 15;                 // column: q (and v for A-frags)
  // XCD-grouped decode: 16 heads of one (b,qb) land on one XCD (share mask+K/V in L2)
  const int r8 = blockIdx.x & 7;
  const int q8 = blockIdx.x >> 3;
  const int h  = q8 & 15;
  const int gg = (q8 >> 4) * 8 + r8;       // group 0..63 = b*16+qb
  const int b  = gg >> 4, qb = gg & 15;
  const int q0 = qb * 128 + w * 32;

  const u16* qbh = Qh + ((size_t)(b * H_ + h) * N_) * 64;
  const u16* qbl = Ql + ((size_t)(b * H_ + h) * N_) * 64;
  // per-lane running base pointers
  const u16* kph = Kh + (size_t)b * M_ * 64 + c * 64 + g * 8;
  const u16* kpl = Kl + (size_t)b * M_ * 64 + c * 64 + g * 8;
  const u16* vp  = VT + (size_t)b * 64 * M_ + (size_t)c * M_ + g * 8;
  u16* pl = &plds[w][0];

  const float* mrow[2];
#pragma unroll
  for (int qt = 0; qt < 2; qt++)
    mrow[qt] = mask + (size_t)b * N_ * M_ + (size_t)(q0 + qt * 16 + c) * M_ + g * 4;

  // Q fragments (B-operand): col=c -> q
  s16x8 fqh[2][2], fql[2][2];
#pragma unroll
  for (int qt = 0; qt < 2; qt++)
#pragma unroll
    for (int kc = 0; kc < 2; kc++){
      const int row = q0 + qt * 16 + c;
      const size_t off = (size_t)row * 64 + kc * 32 + g * 8;
      fqh[qt][kc] = *(const s16x8*)(qbh + off);
      fql[qt][kc] = *(const s16x8*)(qbl + off);
    }

  f32x4 acc[2][4];
#pragma unroll
  for (int qt = 0; qt < 2; qt++)
#pragma unroll
    for (int vt = 0; vt < 4; vt++) acc[qt][vt] = f32x4{0.f, 0.f, 0.f, 0.f};
  float mrun[2] = {-INFINITY, -INFINITY};
  float lrun[2] = {0.f, 0.f};

  // K register double-buffer; 2-step unrolled loop keeps all indexing static
  s16x8 kh0[2][2], kl0[2][2], kh1[2][2], kl1[2][2];
  loadK(kh0, kl0, kph, kpl, 0);
  for (int m0 = 0; m0 < M_; m0 += 64){
    attn_step(kh0, kl0, kh1, kl1, m0,      fqh, fql, acc, mrun, lrun, mrow, vp, kph, kpl, pl, c, g);
    attn_step(kh1, kl1, kh0, kl0, m0 + 32, fqh, fql, acc, mrun, lrun, mrow, vp, kph, kpl, pl, c, g);
  }

  // epilogue: reduce deferred row sums over the 4-lane column group, /l, store O'
#pragma unroll
  for (int qt = 0; qt < 2; qt++){
    float tot = lrun[qt];
    tot += __shfl_xor(tot, 16, 64);
    tot += __shfl_xor(tot, 32, 64);
    const float inv = 1.0f / tot;
    const int qq = q0 + qt * 16 + c;
    const size_t rowbase = ((size_t)(b * N_ + qq)) * 1024 + h * 64;
#pragma unroll
    for (int vt = 0; vt < 4; vt++){
      ushort4 ph, plo;
      u16 hh, ll;
      split2(acc[qt][vt][0] * inv, hh, ll); ph.x = hh; plo.x = ll;
      split2(acc[qt][vt][1] * inv, hh, ll); ph.y = hh; plo.y = ll;
      split2(acc[qt][vt][2] * inv, hh, ll); ph.z = hh; plo.z = ll;
      split2(acc[qt][vt][3] * inv, hh, ll); ph.w = hh; plo.w = ll;
      const size_t idx = rowbase + vt * 16 + g * 4;
      *(ushort4*)(Oh + idx) = ph;
      *(ushort4*)(Ol + idx) = plo;
    }
  }
}

// ---------- host launcher ----------
extern "C" void kernel_launch(void* const* d_in, const int* in_sizes, int n_in,
                              void* d_out, int out_size, void* d_ws, size_t ws_size,
                              hipStream_t stream){
  const float* X  = (const float*)d_in[0];
  const float* Mi = (const float*)d_in[1];
  const float* mask = (const float*)d_in[2];
  const float* Pq = (const float*)d_in[3];
  const float* Pk = (const float*)d_in[4];
  const float* Pv = (const float*)d_in[5];
  const float* Po = (const float*)d_in[6];
  float* Y = (float*)d_out;

  char* ws = (char*)d_ws;
  auto alloc = [&](size_t bytes) -> char* {
    char* p = ws;
    ws += (bytes + 255) & ~(size_t)255;
    return p;
  };
  const size_t SZ_XM = (size_t)ROWS * D_ * 2;        // 16 MiB
  u16* Xh = (u16*)alloc(SZ_XM);
  u16* Xl = (u16*)alloc(SZ_XM);
  u16* Mh = (u16*)alloc(SZ_XM);
  u16* Ml = (u16*)alloc(SZ_XM);
  u16* PqTh = (u16*)alloc(1024 * 1024 * 2);
  u16* PqTl = (u16*)alloc(1024 * 1024 * 2);
  u16* PkvTh = (u16*)alloc(128 * 1024 * 2);
  u16* PkvTl = (u16*)alloc(128 * 1024 * 2);
  u16* WoTh = (u16*)alloc(1024 * 1024 * 2);
  u16* WoTl = (u16*)alloc(1024 * 1024 * 2);
  u16* Qh = (u16*)alloc(SZ_XM);
  u16* Ql = (u16*)alloc(SZ_XM);
  u16* Kh = (u16*)alloc((size_t)B_ * M_ * 64 * 2);
  u16* Kl = (u16*)alloc((size_t)B_ * M_ * 64 * 2);
  u16* VT = (u16*)alloc((size_t)B_ * M_ * 64 * 2);
  u16* Oh = (u16*)alloc(SZ_XM);
  u16* Ol = (u16*)alloc(SZ_XM);
  if ((size_t)(ws - (char*)d_ws) > ws_size) return;

  split_xm<<<2048, 256, 0, stream>>>(X, Mi, Xh, Xl, Mh, Ml);
  transform_w<<<1024, 256, 0, stream>>>(Pq, Pk, Pv, Po, PqTh, PqTl, PkvTh, PkvTl, WoTh, WoTl);
  gemm3<1><<<dim3(1, 64), 256, 0, stream>>>(Mh, Ml, PkvTh, PkvTl, Kh, Kl, VT);
  gemm3<0><<<dim3(8, 64), 256, 0, stream>>>(Xh, Xl, PqTh, PqTl, Qh, Ql, nullptr);
  attn<<<1024, 256, 0, stream>>>(Qh, Ql, Kh, Kl, VT, mask, Oh, Ol);
  gemm3<2><<<dim3(8, 64), 256, 0, stream>>>(Oh, Ol, WoTh, WoTl, Y, nullptr, nullptr);
}

// Round 6
// 550.801 us; speedup vs baseline: 1.3467x; 1.3467x over previous
//
#include <hip/hip_runtime.h>
#include <cstdint>
#include <cstddef>

typedef unsigned short u16;
typedef unsigned int   u32;
typedef short s16x8 __attribute__((ext_vector_type(8)));   // 8 bf16 bit-patterns (4 VGPRs)
typedef float f32x4 __attribute__((ext_vector_type(4)));

#define B_   4
#define H_   16
#define N_   2048
#define M_   2048
#define D_   1024
#define ROWS 8192   // B_*N_ == B_*M_

// ---------- scalar helpers ----------
__device__ __forceinline__ u16 f2bf(float x){
  u32 u = __builtin_bit_cast(u32, x);
  u = (u + 0x7fffu + ((u >> 16) & 1u)) >> 16;   // RNE truncate to bf16
  return (u16)u;
}
__device__ __forceinline__ float bf2f(u16 h){
  u32 u = ((u32)h) << 16;
  return __builtin_bit_cast(float, u);
}
__device__ __forceinline__ void split2(float v, u16 &h, u16 &l){
  h = f2bf(v);
  l = f2bf(v - bf2f(h));
}
__device__ __forceinline__ void gload16(const void* g, void* l){
  __builtin_amdgcn_global_load_lds((const __attribute__((address_space(1))) u32*)g,
                                   (__attribute__((address_space(3))) u32*)l, 16, 0, 0);
}
__device__ __forceinline__ f32x4 mfma16(s16x8 a, s16x8 b, f32x4 c){
  return __builtin_amdgcn_mfma_f32_16x16x32_bf16(a, b, c, 0, 0, 0);
}

// ---------- kernel 1: split X and M into bf16 hi/lo ----------
__global__ void split_xm(const float* __restrict__ X, const float* __restrict__ Mi,
                         u16* __restrict__ Xh, u16* __restrict__ Xl,
                         u16* __restrict__ Mh, u16* __restrict__ Ml){
  const int n4 = ROWS * D_ / 4;
  for (int i = blockIdx.x * blockDim.x + threadIdx.x; i < n4; i += gridDim.x * blockDim.x){
    float4 x = ((const float4*)X)[i];
    float4 m = ((const float4*)Mi)[i];
    ushort4 xh, xl, mh, ml;
    split2(x.x, xh.x, xl.x); split2(x.y, xh.y, xl.y);
    split2(x.z, xh.z, xl.z); split2(x.w, xh.w, xl.w);
    split2(m.x, mh.x, ml.x); split2(m.y, mh.y, ml.y);
    split2(m.z, mh.z, ml.z); split2(m.w, mh.w, ml.w);
    ((ushort4*)Xh)[i] = xh; ((ushort4*)Xl)[i] = xl;
    ((ushort4*)Mh)[i] = mh; ((ushort4*)Ml)[i] = ml;
  }
}

// ---------- kernel 2: weight transposes + hi/lo splits ----------
__global__ void transform_w(const float* __restrict__ Pq, const float* __restrict__ Pk,
                            const float* __restrict__ Pv, const float* __restrict__ Po,
                            u16* __restrict__ PqTh, u16* __restrict__ PqTl,
                            u16* __restrict__ PkvTh, u16* __restrict__ PkvTl,
                            u16* __restrict__ WoTh, u16* __restrict__ WoTl){
  const int TOT = 1048576 + 131072 + 1048576;
  for (int gid = blockIdx.x * blockDim.x + threadIdx.x; gid < TOT; gid += gridDim.x * blockDim.x){
    float v; u16 *oh, *ol; int oidx;
    if (gid < 1048576){
      int c = gid >> 10, d = gid & 1023;
      v = Pq[(size_t)(c >> 6) * 65536 + d * 64 + (c & 63)];
      oh = PqTh; ol = PqTl; oidx = gid;
    } else if (gid < 1048576 + 131072){
      int t = gid - 1048576; int c = t >> 10, d = t & 1023;
      v = (c < 64) ? Pk[d * 64 + c] : Pv[d * 64 + (c - 64)];
      oh = PkvTh; ol = PkvTl; oidx = t;
    } else {
      int t = gid - (1048576 + 131072); int dd = t >> 10, hv = t & 1023;
      v = Po[(size_t)(hv >> 6) * 65536 + dd * 64 + (hv & 63)];
      oh = WoTh; ol = WoTl; oidx = t;
    }
    u16 h, l; split2(v, h, l);
    oh[oidx] = h; ol[oidx] = l;
  }
}

// ---------- shared GEMM (unchanged this round) ----------
template<int MODE>
__global__ __launch_bounds__(256, 2)
void gemm3(const u16* __restrict__ Ah, const u16* __restrict__ Al,
           const u16* __restrict__ Bh, const u16* __restrict__ Bl,
           void* __restrict__ o0, void* __restrict__ o1, void* __restrict__ o2){
  __shared__ __align__(16) u16 lds[2][4][128 * 32];
  const int tid = threadIdx.x;
  const int lane = tid & 63;
  const int w = tid >> 6;
  const int wr = w >> 1, wc = w & 1;
  const int br0 = blockIdx.y * 128;
  const int bc0 = blockIdx.x * 128;

  const u16* srcs[4] = {Ah, Al, Bh, Bl};

  auto stage = [&](int buf, int s){
    const int k0 = s * 32;
#pragma unroll
    for (int t = 0; t < 4; t++){
      const u16* src = srcs[t];
      const int rbase = (t >= 2) ? bc0 : br0;
#pragma unroll
      for (int it = 0; it < 2; it++){
        const int c1k = w * 2 + it;
        const int ci = c1k * 64 + lane;
        const int row = ci >> 2;
        const int gs = (ci & 3) ^ ((row >> 1) & 3);
        gload16(src + (size_t)(rbase + row) * 1024 + k0 + gs * 8,
                &lds[buf][t][c1k * 512]);
      }
    }
  };

  f32x4 acc[4][4];
#pragma unroll
  for (int i = 0; i < 4; i++)
#pragma unroll
    for (int j = 0; j < 4; j++) acc[i][j] = f32x4{0.f, 0.f, 0.f, 0.f};

  stage(0, 0);
  for (int s = 0; s < 32; s++){
    __syncthreads();
    if (s + 1 < 32) stage((s + 1) & 1, s + 1);
    const int buf = s & 1;
    const int g = lane >> 4;
    s16x8 fah[4], fal[4], fbh[4], fbl[4];
#pragma unroll
    for (int i = 0; i < 4; i++){
      const int ra = wr * 64 + i * 16 + (lane & 15);
      const int oa = ra * 64 + ((g ^ ((ra >> 1) & 3)) * 16);
      fah[i] = *(const s16x8*)((const char*)&lds[buf][0][0] + oa);
      fal[i] = *(const s16x8*)((const char*)&lds[buf][1][0] + oa);
      const int rb = wc * 64 + i * 16 + (lane & 15);
      const int ob = rb * 64 + ((g ^ ((rb >> 1) & 3)) * 16);
      fbh[i] = *(const s16x8*)((const char*)&lds[buf][2][0] + ob);
      fbl[i] = *(const s16x8*)((const char*)&lds[buf][3][0] + ob);
    }
#pragma unroll
    for (int i = 0; i < 4; i++)
#pragma unroll
      for (int j = 0; j < 4; j++){
        acc[i][j] = mfma16(fah[i], fbh[j], acc[i][j]);
        acc[i][j] = mfma16(fah[i], fbl[j], acc[i][j]);
        acc[i][j] = mfma16(fal[i], fbh[j], acc[i][j]);
      }
  }

#pragma unroll
  for (int i = 0; i < 4; i++){
#pragma unroll
    for (int j = 0; j < 4; j++){
#pragma unroll
      for (int r = 0; r < 4; r++){
        const int row = br0 + wr * 64 + i * 16 + (lane >> 4) * 4 + r;
        const int col = bc0 + wc * 64 + j * 16 + (lane & 15);
        const float v = acc[i][j][r];
        if (MODE == 0){
          const int b = row >> 11, n = row & 2047;
          const int h = col >> 6,  k = col & 63;
          const size_t idx = ((size_t)(b * H_ + h) * N_ + n) * 64 + k;
          u16 hh, ll; split2(v, hh, ll);
          ((u16*)o0)[idx] = hh; ((u16*)o1)[idx] = ll;
        } else if (MODE == 1){
          if (col < 64){
            const size_t idx = (size_t)row * 64 + col;
            u16 hh, ll; split2(v, hh, ll);
            ((u16*)o0)[idx] = hh; ((u16*)o1)[idx] = ll;
          } else {
            const int b = row >> 11, m = row & 2047;
            const size_t idx = (size_t)b * (64 * 2048) + (size_t)(col - 64) * 2048 + m;
            ((u16*)o2)[idx] = f2bf(v);
          }
        } else {
          ((float*)o0)[(size_t)row * 1024 + col] = v;
        }
      }
    }
  }
}

// ---------- kernel 5: flash attention (LDS-staged, head-sharing blocks) ----------
// Block = 4 waves = 4 heads (hg*4+w) x SAME 32 q-rows. Per m-tile (32 rows):
// K(h+l) 8KB + V^T 4KB + mask 4KB staged once per block via global_load_lds
// (linear dst, inverse-swizzled per-lane source), double-buffered, 1 barrier/iter.
// Fragment reads from LDS with XOR slot swizzle (slot ^= row&7 for 128B rows,
// slot ^= row&3 for 64B rows). Swapped-operand MFMA as r5.
__global__ __launch_bounds__(256, 3)
void attn(const u16* __restrict__ Qh, const u16* __restrict__ Ql,
          const u16* __restrict__ Kh, const u16* __restrict__ Kl,
          const u16* __restrict__ VT, const float* __restrict__ mask,
          u16* __restrict__ Oh, u16* __restrict__ Ol){
  __shared__ __align__(16) u16  khb[2][2048];   // 32 m-rows x 64 u16 (128B rows), swizzled
  __shared__ __align__(16) u16  klb[2][2048];
  __shared__ __align__(16) u16  vb [2][2048];   // 64 v-rows x 32 u16 (64B rows), swizzled
  __shared__ __align__(16) float mb[2][1024];   // 32 q-rows x 32 f32 (128B rows), swizzled
  __shared__ __align__(16) u16  pbuf[4][1280];  // per-wave P scratch: 32 x 40 u16

  const int t = threadIdx.x;
  const int lane = t & 63;
  const int w = t >> 6;
  const int g = lane >> 4;                 // 4 lane-groups
  const int c = lane & 15;                 // column index
  // XCD-packed decode: consecutive wgids on one XCD share b (K/V) and q-range (mask)
  const int r8 = blockIdx.x & 7;
  const int i8 = blockIdx.x >> 3;          // 0..127
  const int wgid = r8 * 128 + i8;
  const int b   = wgid >> 8;               // batch
  const int rem = wgid & 255;
  const int q5  = rem >> 2;                // 64 q-blocks of 32 rows
  const int hg  = rem & 3;                 // head group
  const int h   = hg * 4 + w;              // this wave's head
  const int q0  = q5 * 32;

  const u16* qbh = Qh + ((size_t)(b * H_ + h) * N_) * 64;
  const u16* qbl = Ql + ((size_t)(b * H_ + h) * N_) * 64;
  const u16* kgh = Kh + (size_t)b * M_ * 64;
  const u16* kgl = Kl + (size_t)b * M_ * 64;
  const u16* vg  = VT + (size_t)b * 64 * M_;
  const float* mg = mask + (size_t)b * N_ * M_;

  // staging source offsets (per thread), inverse-swizzled (rule #21: same involution
  // on source as on read; LDS dst stays linear = wave-uniform base + lane*16)
  const int sr = t >> 3, sj = t & 7;       // K/mask: row 0..31, 16B-chunk 0..7
  const int vr = t >> 2, vj = t & 3;       // V: row 0..63, 16B-chunk 0..3
  const size_t koff = (size_t)sr * 64 + (size_t)((sj ^ (sr & 7)) * 8);
  const size_t moff = (size_t)(q0 + sr) * M_ + (size_t)((sj ^ (sr & 7)) * 4);
  const size_t voff = (size_t)vr * M_ + (size_t)((vj ^ (vr & 3)) * 8);

  auto stage = [&](int buf, int m0){
    gload16(kgh + (size_t)m0 * 64 + koff, &khb[buf][t * 8]);
    gload16(kgl + (size_t)m0 * 64 + koff, &klb[buf][t * 8]);
    gload16(vg + m0 + voff,               &vb[buf][t * 8]);
    gload16(mg + m0 + moff,               &mb[buf][t * 4]);
  };

  // Q fragments (B-operand), per-head, held in registers for all 64 iters
  s16x8 fqh[2][2], fql[2][2];
#pragma unroll
  for (int qt = 0; qt < 2; qt++)
#pragma unroll
    for (int kc = 0; kc < 2; kc++){
      const size_t off = (size_t)(q0 + qt * 16 + c) * 64 + kc * 32 + g * 8;
      fqh[qt][kc] = *(const s16x8*)(qbh + off);
      fql[qt][kc] = *(const s16x8*)(qbl + off);
    }

  f32x4 acc[2][4];
#pragma unroll
  for (int qt = 0; qt < 2; qt++)
#pragma unroll
    for (int vt = 0; vt < 4; vt++) acc[qt][vt] = f32x4{0.f, 0.f, 0.f, 0.f};
  float mrun[2] = {-INFINITY, -INFINITY};
  float lrun[2] = {0.f, 0.f};
  u16* pl = &pbuf[w][0];

  stage(0, 0);
  for (int it = 0; it < 64; ++it){
    const int m0 = it * 32;
    const int cur = it & 1;
    __syncthreads();                       // drains vmcnt -> buf 'cur' staged; prev reads done
    if (it < 63) stage(cur ^ 1, m0 + 32);

    // K fragments from LDS (A-operand): row = mt*16+c, slot = (kc*4+g)^(c&7)
    const char* kh_ = (const char*)khb[cur];
    const char* kl_ = (const char*)klb[cur];
    s16x8 kfh[2][2], kfl[2][2];
#pragma unroll
    for (int mt = 0; mt < 2; mt++)
#pragma unroll
      for (int kc = 0; kc < 2; kc++){
        const int p = (mt * 16 + c) * 128 + (((kc * 4 + g) ^ (c & 7)) * 16);
        kfh[mt][kc] = *(const s16x8*)(kh_ + p);
        kfl[mt][kc] = *(const s16x8*)(kl_ + p);
      }
    // V fragments from LDS (A-operand): row = vt*16+c, slot = g^(c&3)
    const char* v_ = (const char*)vb[cur];
    s16x8 fv[4];
#pragma unroll
    for (int vt = 0; vt < 4; vt++)
      fv[vt] = *(const s16x8*)(v_ + (vt * 16 + c) * 64 + ((g ^ (c & 3)) * 16));

    // S^T = mfma(K, Q), split-3
    f32x4 S[2][2];
#pragma unroll
    for (int qt = 0; qt < 2; qt++)
#pragma unroll
      for (int mt = 0; mt < 2; mt++){
        f32x4 a = f32x4{0.f, 0.f, 0.f, 0.f};
        a = mfma16(kfh[mt][0], fqh[qt][0], a);
        a = mfma16(kfh[mt][1], fqh[qt][1], a);
        a = mfma16(kfl[mt][0], fqh[qt][0], a);
        a = mfma16(kfl[mt][1], fqh[qt][1], a);
        a = mfma16(kfh[mt][0], fql[qt][0], a);
        a = mfma16(kfh[mt][1], fql[qt][1], a);
        S[qt][mt] = a;
      }
    // + mask from LDS: row = qt*16+c, slot = (mt*4+g)^(c&7)
    const char* m_ = (const char*)mb[cur];
#pragma unroll
    for (int qt = 0; qt < 2; qt++)
#pragma unroll
      for (int mt = 0; mt < 2; mt++){
        const f32x4 mk = *(const f32x4*)(m_ + (qt * 16 + c) * 128 + (((mt * 4 + g) ^ (c & 7)) * 16));
        S[qt][mt] = S[qt][mt] + mk;
      }

    // branchless online softmax (lane-local 8-val max, 2 shfl)
#pragma unroll
    for (int qt = 0; qt < 2; qt++){
      float rmax = fmaxf(fmaxf(fmaxf(S[qt][0][0], S[qt][0][1]), fmaxf(S[qt][0][2], S[qt][0][3])),
                         fmaxf(fmaxf(S[qt][1][0], S[qt][1][1]), fmaxf(S[qt][1][2], S[qt][1][3])));
      rmax = fmaxf(rmax, __shfl_xor(rmax, 16, 64));
      rmax = fmaxf(rmax, __shfl_xor(rmax, 32, 64));
      const float mnew = fmaxf(mrun[qt], rmax);
      const float sc = __expf(mrun[qt] - mnew);
      mrun[qt] = mnew;
#pragma unroll
      for (int vt = 0; vt < 4; vt++){
        acc[qt][vt][0] *= sc; acc[qt][vt][1] *= sc;
        acc[qt][vt][2] *= sc; acc[qt][vt][3] *= sc;
      }
      float psum = 0.f;
#pragma unroll
      for (int mt = 0; mt < 2; mt++){
        float p0 = __expf(S[qt][mt][0] - mnew);
        float p1 = __expf(S[qt][mt][1] - mnew);
        float p2 = __expf(S[qt][mt][2] - mnew);
        float p3 = __expf(S[qt][mt][3] - mnew);
        psum += (p0 + p1) + (p2 + p3);
        ushort4 pk;
        pk.x = f2bf(p0); pk.y = f2bf(p1); pk.z = f2bf(p2); pk.w = f2bf(p3);
        *(ushort4*)((char*)pl + (qt * 16 + c) * 80 + mt * 32 + g * 8) = pk;
      }
      lrun[qt] = lrun[qt] * sc + psum;
    }
    // P^T B-frags (same-wave DS ordering)
    s16x8 pb0 = *(const s16x8*)((const char*)pl + c * 80 + g * 16);
    s16x8 pb1 = *(const s16x8*)((const char*)pl + (16 + c) * 80 + g * 16);
    // swapped PV: O^T += mfma(V^T, P^T)
#pragma unroll
    for (int vt = 0; vt < 4; vt++){
      acc[0][vt] = mfma16(fv[vt], pb0, acc[0][vt]);
      acc[1][vt] = mfma16(fv[vt], pb1, acc[1][vt]);
    }
  }

  // epilogue: reduce deferred row sums over the 4-lane column group, /l, store O'
#pragma unroll
  for (int qt = 0; qt < 2; qt++){
    float tot = lrun[qt];
    tot += __shfl_xor(tot, 16, 64);
    tot += __shfl_xor(tot, 32, 64);
    const float inv = 1.0f / tot;
    const int qq = q0 + qt * 16 + c;
    const size_t rowbase = ((size_t)(b * N_ + qq)) * 1024 + h * 64;
#pragma unroll
    for (int vt = 0; vt < 4; vt++){
      ushort4 ph, plo;
      u16 hh, ll;
      split2(acc[qt][vt][0] * inv, hh, ll); ph.x = hh; plo.x = ll;
      split2(acc[qt][vt][1] * inv, hh, ll); ph.y = hh; plo.y = ll;
      split2(acc[qt][vt][2] * inv, hh, ll); ph.z = hh; plo.z = ll;
      split2(acc[qt][vt][3] * inv, hh, ll); ph.w = hh; plo.w = ll;
      const size_t idx = rowbase + vt * 16 + g * 4;
      *(ushort4*)(Oh + idx) = ph;
      *(ushort4*)(Ol + idx) = plo;
    }
  }
}

// ---------- host launcher ----------
extern "C" void kernel_launch(void* const* d_in, const int* in_sizes, int n_in,
                              void* d_out, int out_size, void* d_ws, size_t ws_size,
                              hipStream_t stream){
  const float* X  = (const float*)d_in[0];
  const float* Mi = (const float*)d_in[1];
  const float* mask = (const float*)d_in[2];
  const float* Pq = (const float*)d_in[3];
  const float* Pk = (const float*)d_in[4];
  const float* Pv = (const float*)d_in[5];
  const float* Po = (const float*)d_in[6];
  float* Y = (float*)d_out;

  char* ws = (char*)d_ws;
  auto alloc = [&](size_t bytes) -> char* {
    char* p = ws;
    ws += (bytes + 255) & ~(size_t)255;
    return p;
  };
  const size_t SZ_XM = (size_t)ROWS * D_ * 2;        // 16 MiB
  u16* Xh = (u16*)alloc(SZ_XM);
  u16* Xl = (u16*)alloc(SZ_XM);
  u16* Mh = (u16*)alloc(SZ_XM);
  u16* Ml = (u16*)alloc(SZ_XM);
  u16* PqTh = (u16*)alloc(1024 * 1024 * 2);
  u16* PqTl = (u16*)alloc(1024 * 1024 * 2);
  u16* PkvTh = (u16*)alloc(128 * 1024 * 2);
  u16* PkvTl = (u16*)alloc(128 * 1024 * 2);
  u16* WoTh = (u16*)alloc(1024 * 1024 * 2);
  u16* WoTl = (u16*)alloc(1024 * 1024 * 2);
  u16* Qh = (u16*)alloc(SZ_XM);
  u16* Ql = (u16*)alloc(SZ_XM);
  u16* Kh = (u16*)alloc((size_t)B_ * M_ * 64 * 2);
  u16* Kl = (u16*)alloc((size_t)B_ * M_ * 64 * 2);
  u16* VT = (u16*)alloc((size_t)B_ * M_ * 64 * 2);
  u16* Oh = (u16*)alloc(SZ_XM);
  u16* Ol = (u16*)alloc(SZ_XM);
  if ((size_t)(ws - (char*)d_ws) > ws_size) return;

  split_xm<<<2048, 256, 0, stream>>>(X, Mi, Xh, Xl, Mh, Ml);
  transform_w<<<1024, 256, 0, stream>>>(Pq, Pk, Pv, Po, PqTh, PqTl, PkvTh, PkvTl, WoTh, WoTl);
  gemm3<1><<<dim3(1, 64), 256, 0, stream>>>(Mh, Ml, PkvTh, PkvTl, Kh, Kl, VT);
  gemm3<0><<<dim3(8, 64), 256, 0, stream>>>(Xh, Xl, PqTh, PqTl, Qh, Ql, nullptr);
  attn<<<1024, 256, 0, stream>>>(Qh, Ql, Kh, Kl, VT, mask, Oh, Ol);
  gemm3<2><<<dim3(8, 64), 256, 0, stream>>>(Oh, Ol, WoTh, WoTl, Y, nullptr, nullptr);
}

// Round 7
// 494.696 us; speedup vs baseline: 1.4994x; 1.1134x over previous
//
#include <hip/hip_runtime.h>
#include <hip/hip_bf16.h>
#include <cstdint>
#include <cstddef>

typedef unsigned short u16;
typedef unsigned int   u32;
typedef short s16x8 __attribute__((ext_vector_type(8)));   // 8 bf16 bit-patterns (4 VGPRs)
typedef float f32x4 __attribute__((ext_vector_type(4)));

#define B_   4
#define H_   16
#define N_   2048
#define M_   2048
#define D_   1024
#define ROWS 8192   // B_*N_ == B_*M_

// ---------- scalar helpers ----------
__device__ __forceinline__ u16 f2bf(float x){
  u32 u = __builtin_bit_cast(u32, x);
  u = (u + 0x7fffu + ((u >> 16) & 1u)) >> 16;   // RNE truncate to bf16
  return (u16)u;
}
__device__ __forceinline__ float bf2f(u16 h){
  u32 u = ((u32)h) << 16;
  return __builtin_bit_cast(float, u);
}
__device__ __forceinline__ void split2(float v, u16 &h, u16 &l){
  h = f2bf(v);
  l = f2bf(v - bf2f(h));
}
__device__ __forceinline__ u16 fbhw(float x){            // hardware bf16 convert
  return __builtin_bit_cast(u16, __float2bfloat16(x));
}
__device__ __forceinline__ void gload16(const void* g, void* l){
  __builtin_amdgcn_global_load_lds((const __attribute__((address_space(1))) u32*)g,
                                   (__attribute__((address_space(3))) u32*)l, 16, 0, 0);
}
__device__ __forceinline__ f32x4 mfma16(s16x8 a, s16x8 b, f32x4 c){
  return __builtin_amdgcn_mfma_f32_16x16x32_bf16(a, b, c, 0, 0, 0);
}

// ---------- kernel 1: split X and M into bf16 hi/lo ----------
__global__ void split_xm(const float* __restrict__ X, const float* __restrict__ Mi,
                         u16* __restrict__ Xh, u16* __restrict__ Xl,
                         u16* __restrict__ Mh, u16* __restrict__ Ml){
  const int n4 = ROWS * D_ / 4;
  for (int i = blockIdx.x * blockDim.x + threadIdx.x; i < n4; i += gridDim.x * blockDim.x){
    float4 x = ((const float4*)X)[i];
    float4 m = ((const float4*)Mi)[i];
    ushort4 xh, xl, mh, ml;
    split2(x.x, xh.x, xl.x); split2(x.y, xh.y, xl.y);
    split2(x.z, xh.z, xl.z); split2(x.w, xh.w, xl.w);
    split2(m.x, mh.x, ml.x); split2(m.y, mh.y, ml.y);
    split2(m.z, mh.z, ml.z); split2(m.w, mh.w, ml.w);
    ((ushort4*)Xh)[i] = xh; ((ushort4*)Xl)[i] = xl;
    ((ushort4*)Mh)[i] = mh; ((ushort4*)Ml)[i] = ml;
  }
}

// ---------- kernel 2: weight transposes + hi/lo splits ----------
__global__ void transform_w(const float* __restrict__ Pq, const float* __restrict__ Pk,
                            const float* __restrict__ Pv, const float* __restrict__ Po,
                            u16* __restrict__ PqTh, u16* __restrict__ PqTl,
                            u16* __restrict__ PkvTh, u16* __restrict__ PkvTl,
                            u16* __restrict__ WoTh, u16* __restrict__ WoTl){
  const int TOT = 1048576 + 131072 + 1048576;
  for (int gid = blockIdx.x * blockDim.x + threadIdx.x; gid < TOT; gid += gridDim.x * blockDim.x){
    float v; u16 *oh, *ol; int oidx;
    if (gid < 1048576){
      int c = gid >> 10, d = gid & 1023;
      v = Pq[(size_t)(c >> 6) * 65536 + d * 64 + (c & 63)];
      oh = PqTh; ol = PqTl; oidx = gid;
    } else if (gid < 1048576 + 131072){
      int t = gid - 1048576; int c = t >> 10, d = t & 1023;
      v = (c < 64) ? Pk[d * 64 + c] : Pv[d * 64 + (c - 64)];
      oh = PkvTh; ol = PkvTl; oidx = t;
    } else {
      int t = gid - (1048576 + 131072); int dd = t >> 10, hv = t & 1023;
      v = Po[(size_t)(hv >> 6) * 65536 + dd * 64 + (hv & 63)];
      oh = WoTh; ol = WoTl; oidx = t;
    }
    u16 h, l; split2(v, h, l);
    oh[oidx] = h; ol[oidx] = l;
  }
}

// ---------- shared GEMM (unchanged this round) ----------
template<int MODE>
__global__ __launch_bounds__(256, 2)
void gemm3(const u16* __restrict__ Ah, const u16* __restrict__ Al,
           const u16* __restrict__ Bh, const u16* __restrict__ Bl,
           void* __restrict__ o0, void* __restrict__ o1, void* __restrict__ o2){
  __shared__ __align__(16) u16 lds[2][4][128 * 32];
  const int tid = threadIdx.x;
  const int lane = tid & 63;
  const int w = tid >> 6;
  const int wr = w >> 1, wc = w & 1;
  const int br0 = blockIdx.y * 128;
  const int bc0 = blockIdx.x * 128;

  const u16* srcs[4] = {Ah, Al, Bh, Bl};

  auto stage = [&](int buf, int s){
    const int k0 = s * 32;
#pragma unroll
    for (int t = 0; t < 4; t++){
      const u16* src = srcs[t];
      const int rbase = (t >= 2) ? bc0 : br0;
#pragma unroll
      for (int it = 0; it < 2; it++){
        const int c1k = w * 2 + it;
        const int ci = c1k * 64 + lane;
        const int row = ci >> 2;
        const int gs = (ci & 3) ^ ((row >> 1) & 3);
        gload16(src + (size_t)(rbase + row) * 1024 + k0 + gs * 8,
                &lds[buf][t][c1k * 512]);
      }
    }
  };

  f32x4 acc[4][4];
#pragma unroll
  for (int i = 0; i < 4; i++)
#pragma unroll
    for (int j = 0; j < 4; j++) acc[i][j] = f32x4{0.f, 0.f, 0.f, 0.f};

  stage(0, 0);
  for (int s = 0; s < 32; s++){
    __syncthreads();
    if (s + 1 < 32) stage((s + 1) & 1, s + 1);
    const int buf = s & 1;
    const int g = lane >> 4;
    s16x8 fah[4], fal[4], fbh[4], fbl[4];
#pragma unroll
    for (int i = 0; i < 4; i++){
      const int ra = wr * 64 + i * 16 + (lane & 15);
      const int oa = ra * 64 + ((g ^ ((ra >> 1) & 3)) * 16);
      fah[i] = *(const s16x8*)((const char*)&lds[buf][0][0] + oa);
      fal[i] = *(const s16x8*)((const char*)&lds[buf][1][0] + oa);
      const int rb = wc * 64 + i * 16 + (lane & 15);
      const int ob = rb * 64 + ((g ^ ((rb >> 1) & 3)) * 16);
      fbh[i] = *(const s16x8*)((const char*)&lds[buf][2][0] + ob);
      fbl[i] = *(const s16x8*)((const char*)&lds[buf][3][0] + ob);
    }
#pragma unroll
    for (int i = 0; i < 4; i++)
#pragma unroll
      for (int j = 0; j < 4; j++){
        acc[i][j] = mfma16(fah[i], fbh[j], acc[i][j]);
        acc[i][j] = mfma16(fah[i], fbl[j], acc[i][j]);
        acc[i][j] = mfma16(fal[i], fbh[j], acc[i][j]);
      }
  }

#pragma unroll
  for (int i = 0; i < 4; i++){
#pragma unroll
    for (int j = 0; j < 4; j++){
#pragma unroll
      for (int r = 0; r < 4; r++){
        const int row = br0 + wr * 64 + i * 16 + (lane >> 4) * 4 + r;
        const int col = bc0 + wc * 64 + j * 16 + (lane & 15);
        const float v = acc[i][j][r];
        if (MODE == 0){
          const int b = row >> 11, n = row & 2047;
          const int h = col >> 6,  k = col & 63;
          const size_t idx = ((size_t)(b * H_ + h) * N_ + n) * 64 + k;
          u16 hh, ll; split2(v, hh, ll);
          ((u16*)o0)[idx] = hh; ((u16*)o1)[idx] = ll;
        } else if (MODE == 1){
          if (col < 64){
            const size_t idx = (size_t)row * 64 + col;
            u16 hh, ll; split2(v, hh, ll);
            ((u16*)o0)[idx] = hh; ((u16*)o1)[idx] = ll;
          } else {
            const int b = row >> 11, m = row & 2047;
            const size_t idx = (size_t)b * (64 * 2048) + (size_t)(col - 64) * 2048 + m;
            ((u16*)o2)[idx] = f2bf(v);
          }
        } else {
          ((float*)o0)[(size_t)row * 1024 + col] = v;
        }
      }
    }
  }
}

// ---------- kernel 5: flash attention (LDS-staged, zero-shuffle PV) ----------
// Block = 4 waves = 4 heads x SAME 32 q-rows. K staged with ROW PERMUTATION
// pi(j): j=[mt g1 g0 r1 r0] -> phys m=[g1 g0 mt r1 r0], so each lane's S values
// land exactly at the logical-m slots (g*8 + mt*4 + r) its PV B-fragment needs:
// P is packed bf16 lane-locally (hardware cvt), NO LDS round-trip, no shuffles.
// Softmax permutation-invariant; mask read at logical chunk 2g+mt (consecutive).
// LDS 32KB -> 4 blocks/CU (grid-capped); exact defer-rescale (__any, sc==1 else).
__global__ __launch_bounds__(256, 4)
void attn(const u16* __restrict__ Qh, const u16* __restrict__ Ql,
          const u16* __restrict__ Kh, const u16* __restrict__ Kl,
          const u16* __restrict__ VT, const float* __restrict__ mask,
          u16* __restrict__ Oh, u16* __restrict__ Ol){
  __shared__ __align__(16) u16  khb[2][2048];   // 32 m-rows x 64 u16 (128B rows), row-permuted + chunk-swizzled
  __shared__ __align__(16) u16  klb[2][2048];
  __shared__ __align__(16) u16  vb [2][2048];   // 64 v-rows x 32 u16 (64B rows), chunk-swizzled
  __shared__ __align__(16) float mb[2][1024];   // 32 q-rows x 32 f32 (128B rows), chunk-swizzled

  const int t = threadIdx.x;
  const int lane = t & 63;
  const int w = t >> 6;
  const int g = lane >> 4;                 // 4 lane-groups
  const int c = lane & 15;                 // column index
  // XCD-packed decode: consecutive wgids on one XCD share b (K/V) and q-range (mask)
  const int r8 = blockIdx.x & 7;
  const int i8 = blockIdx.x >> 3;          // 0..127
  const int wgid = r8 * 128 + i8;
  const int b   = wgid >> 8;               // batch
  const int rem = wgid & 255;
  const int q5  = rem >> 2;                // 64 q-blocks of 32 rows
  const int hg  = rem & 3;                 // head group
  const int h   = hg * 4 + w;              // this wave's head
  const int q0  = q5 * 32;

  const u16* qbh = Qh + ((size_t)(b * H_ + h) * N_) * 64;
  const u16* qbl = Ql + ((size_t)(b * H_ + h) * N_) * 64;
  const u16* kgh = Kh + (size_t)b * M_ * 64;
  const u16* kgl = Kl + (size_t)b * M_ * 64;
  const u16* vg  = VT + (size_t)b * 64 * M_;
  const float* mg = mask + (size_t)b * N_ * M_;

  // staging source offsets (per thread). LDS dst linear (rule #21); source carries
  // the chunk swizzle involution AND (for K) the row permutation pi.
  const int sr = t >> 3, sj = t & 7;       // K/mask: LDS row 0..31, 16B-chunk 0..7
  const int vr = t >> 2, vj = t & 3;       // V: LDS row 0..63, 16B-chunk 0..3
  const int prow = ((sr >> 2) & 3) * 8 + ((sr >> 4) & 1) * 4 + (sr & 3);  // pi(sr)
  const size_t koff = (size_t)prow * 64 + (size_t)((sj ^ (sr & 7)) * 8);
  const size_t moff = (size_t)(q0 + sr) * M_ + (size_t)((sj ^ (sr & 7)) * 4);
  const size_t voff = (size_t)vr * M_ + (size_t)((vj ^ (vr & 3)) * 8);

  auto stage = [&](int buf, int m0){
    gload16(kgh + (size_t)m0 * 64 + koff, &khb[buf][t * 8]);
    gload16(kgl + (size_t)m0 * 64 + koff, &klb[buf][t * 8]);
    gload16(vg + m0 + voff,               &vb[buf][t * 8]);
    gload16(mg + m0 + moff,               &mb[buf][t * 4]);
  };

  // Q fragments (B-operand), per-head, held in registers for all 64 iters
  s16x8 fqh[2][2], fql[2][2];
#pragma unroll
  for (int qt = 0; qt < 2; qt++)
#pragma unroll
    for (int kc = 0; kc < 2; kc++){
      const size_t off = (size_t)(q0 + qt * 16 + c) * 64 + kc * 32 + g * 8;
      fqh[qt][kc] = *(const s16x8*)(qbh + off);
      fql[qt][kc] = *(const s16x8*)(qbl + off);
    }

  f32x4 acc[2][4];
#pragma unroll
  for (int qt = 0; qt < 2; qt++)
#pragma unroll
    for (int vt = 0; vt < 4; vt++) acc[qt][vt] = f32x4{0.f, 0.f, 0.f, 0.f};
  float mrun[2] = {-INFINITY, -INFINITY};
  float lrun[2] = {0.f, 0.f};

  stage(0, 0);
  for (int it = 0; it < 64; ++it){
    const int m0 = it * 32;
    const int cur = it & 1;
    __syncthreads();                       // drains vmcnt -> buf 'cur' staged; prev reads done
    if (it < 63) stage(cur ^ 1, m0 + 32);

    // K fragments from LDS (A-operand): row = mt*16+c, slot = (kc*4+g)^(c&7)
    const char* kh_ = (const char*)khb[cur];
    const char* kl_ = (const char*)klb[cur];
    s16x8 kfh[2][2], kfl[2][2];
#pragma unroll
    for (int mt = 0; mt < 2; mt++)
#pragma unroll
      for (int kc = 0; kc < 2; kc++){
        const int p = (mt * 16 + c) * 128 + (((kc * 4 + g) ^ (c & 7)) * 16);
        kfh[mt][kc] = *(const s16x8*)(kh_ + p);
        kfl[mt][kc] = *(const s16x8*)(kl_ + p);
      }
    // V fragments from LDS (A-operand): row = vt*16+c, slot = g^(c&3)
    const char* v_ = (const char*)vb[cur];
    s16x8 fv[4];
#pragma unroll
    for (int vt = 0; vt < 4; vt++)
      fv[vt] = *(const s16x8*)(v_ + (vt * 16 + c) * 64 + ((g ^ (c & 3)) * 16));

    // S^T = mfma(K, Q), split-3.  Output row j (= LDS K row) holds phys m = pi(j):
    // lane (g,c) gets (mt,r) -> phys m-offset g*8 + mt*4 + r.
    f32x4 S[2][2];
#pragma unroll
    for (int qt = 0; qt < 2; qt++)
#pragma unroll
      for (int mt = 0; mt < 2; mt++){
        f32x4 a = f32x4{0.f, 0.f, 0.f, 0.f};
        a = mfma16(kfh[mt][0], fqh[qt][0], a);
        a = mfma16(kfh[mt][1], fqh[qt][1], a);
        a = mfma16(kfl[mt][0], fqh[qt][0], a);
        a = mfma16(kfl[mt][1], fqh[qt][1], a);
        a = mfma16(kfh[mt][0], fql[qt][0], a);
        a = mfma16(kfh[mt][1], fql[qt][1], a);
        S[qt][mt] = a;
      }
    // + mask from LDS: row = qt*16+c, logical chunk 2g+mt (phys m = g*8+mt*4+0..3)
    const char* m_ = (const char*)mb[cur];
#pragma unroll
    for (int qt = 0; qt < 2; qt++)
#pragma unroll
      for (int mt = 0; mt < 2; mt++){
        const f32x4 mk = *(const f32x4*)(m_ + (qt * 16 + c) * 128 + (((2 * g + mt) ^ (c & 7)) * 16));
        S[qt][mt] = S[qt][mt] + mk;
      }

    // online softmax: lane-local 8-val max, 2 shfl; exact skip-rescale (sc==1 else)
#pragma unroll
    for (int qt = 0; qt < 2; qt++){
      float rmax = fmaxf(fmaxf(fmaxf(S[qt][0][0], S[qt][0][1]), fmaxf(S[qt][0][2], S[qt][0][3])),
                         fmaxf(fmaxf(S[qt][1][0], S[qt][1][1]), fmaxf(S[qt][1][2], S[qt][1][3])));
      rmax = fmaxf(rmax, __shfl_xor(rmax, 16, 64));
      rmax = fmaxf(rmax, __shfl_xor(rmax, 32, 64));
      if (__any(rmax > mrun[qt])){
        const float mnew = fmaxf(mrun[qt], rmax);
        const float sc = __expf(mrun[qt] - mnew);
        mrun[qt] = mnew;
        lrun[qt] *= sc;
#pragma unroll
        for (int vt = 0; vt < 4; vt++){
          acc[qt][vt][0] *= sc; acc[qt][vt][1] *= sc;
          acc[qt][vt][2] *= sc; acc[qt][vt][3] *= sc;
        }
      }
      // P packed lane-locally: word order i = mt*4+r matches B-frag k = g*8+i
      float psum = 0.f;
      u16 pk[8];
#pragma unroll
      for (int mt = 0; mt < 2; mt++){
        float p0 = __expf(S[qt][mt][0] - mrun[qt]);
        float p1 = __expf(S[qt][mt][1] - mrun[qt]);
        float p2 = __expf(S[qt][mt][2] - mrun[qt]);
        float p3 = __expf(S[qt][mt][3] - mrun[qt]);
        psum += (p0 + p1) + (p2 + p3);
        pk[mt * 4 + 0] = fbhw(p0); pk[mt * 4 + 1] = fbhw(p1);
        pk[mt * 4 + 2] = fbhw(p2); pk[mt * 4 + 3] = fbhw(p3);
      }
      lrun[qt] += psum;
      const s16x8 pb = __builtin_bit_cast(s16x8, pk);
      // swapped PV: O^T += mfma(V^T, P^T) — zero shuffles, zero LDS for P
#pragma unroll
      for (int vt = 0; vt < 4; vt++)
        acc[qt][vt] = mfma16(fv[vt], pb, acc[qt][vt]);
    }
  }

  // epilogue: reduce deferred row sums over the 4-lane column group, /l, store O'
#pragma unroll
  for (int qt = 0; qt < 2; qt++){
    float tot = lrun[qt];
    tot += __shfl_xor(tot, 16, 64);
    tot += __shfl_xor(tot, 32, 64);
    const float inv = 1.0f / tot;
    const int qq = q0 + qt * 16 + c;
    const size_t rowbase = ((size_t)(b * N_ + qq)) * 1024 + h * 64;
#pragma unroll
    for (int vt = 0; vt < 4; vt++){
      ushort4 ph, plo;
      u16 hh, ll;
      split2(acc[qt][vt][0] * inv, hh, ll); ph.x = hh; plo.x = ll;
      split2(acc[qt][vt][1] * inv, hh, ll); ph.y = hh; plo.y = ll;
      split2(acc[qt][vt][2] * inv, hh, ll); ph.z = hh; plo.z = ll;
      split2(acc[qt][vt][3] * inv, hh, ll); ph.w = hh; plo.w = ll;
      const size_t idx = rowbase + vt * 16 + g * 4;
      *(ushort4*)(Oh + idx) = ph;
      *(ushort4*)(Ol + idx) = plo;
    }
  }
}

// ---------- host launcher ----------
extern "C" void kernel_launch(void* const* d_in, const int* in_sizes, int n_in,
                              void* d_out, int out_size, void* d_ws, size_t ws_size,
                              hipStream_t stream){
  const float* X  = (const float*)d_in[0];
  const float* Mi = (const float*)d_in[1];
  const float* mask = (const float*)d_in[2];
  const float* Pq = (const float*)d_in[3];
  const float* Pk = (const float*)d_in[4];
  const float* Pv = (const float*)d_in[5];
  const float* Po = (const float*)d_in[6];
  float* Y = (float*)d_out;

  char* ws = (char*)d_ws;
  auto alloc = [&](size_t bytes) -> char* {
    char* p = ws;
    ws += (bytes + 255) & ~(size_t)255;
    return p;
  };
  const size_t SZ_XM = (size_t)ROWS * D_ * 2;        // 16 MiB
  u16* Xh = (u16*)alloc(SZ_XM);
  u16* Xl = (u16*)alloc(SZ_XM);
  u16* Mh = (u16*)alloc(SZ_XM);
  u16* Ml = (u16*)alloc(SZ_XM);
  u16* PqTh = (u16*)alloc(1024 * 1024 * 2);
  u16* PqTl = (u16*)alloc(1024 * 1024 * 2);
  u16* PkvTh = (u16*)alloc(128 * 1024 * 2);
  u16* PkvTl = (u16*)alloc(128 * 1024 * 2);
  u16* WoTh = (u16*)alloc(1024 * 1024 * 2);
  u16* WoTl = (u16*)alloc(1024 * 1024 * 2);
  u16* Qh = (u16*)alloc(SZ_XM);
  u16* Ql = (u16*)alloc(SZ_XM);
  u16* Kh = (u16*)alloc((size_t)B_ * M_ * 64 * 2);
  u16* Kl = (u16*)alloc((size_t)B_ * M_ * 64 * 2);
  u16* VT = (u16*)alloc((size_t)B_ * M_ * 64 * 2);
  u16* Oh = (u16*)alloc(SZ_XM);
  u16* Ol = (u16*)alloc(SZ_XM);
  if ((size_t)(ws - (char*)d_ws) > ws_size) return;

  split_xm<<<2048, 256, 0, stream>>>(X, Mi, Xh, Xl, Mh, Ml);
  transform_w<<<1024, 256, 0, stream>>>(Pq, Pk, Pv, Po, PqTh, PqTl, PkvTh, PkvTl, WoTh, WoTl);
  gemm3<1><<<dim3(1, 64), 256, 0, stream>>>(Mh, Ml, PkvTh, PkvTl, Kh, Kl, VT);
  gemm3<0><<<dim3(8, 64), 256, 0, stream>>>(Xh, Xl, PqTh, PqTl, Qh, Ql, nullptr);
  attn<<<1024, 256, 0, stream>>>(Qh, Ql, Kh, Kl, VT, mask, Oh, Ol);
  gemm3<2><<<dim3(8, 64), 256, 0, stream>>>(Oh, Ol, WoTh, WoTl, Y, nullptr, nullptr);
}